// Round 1
// baseline (460.106 us; speedup 1.0000x reference)
//
#include <hip/hip_runtime.h>
#include <hip/hip_bf16.h>
#include <math.h>

// Problem constants (from reference)
#define BB 32
#define SS 32
#define DD 768
#define FF 3072
#define EE 8
#define KK 2

// Output layout (float32, concatenated):
//   [0, B*S*D)              moe_result [B,S,D]
//   [B*S*D, +B*K)           select_prob_gate [B,K]
//   [B*S*D+B*K, +B*K)       gate [B,K] (indices as float)
//
// Workspace layout:
//   [0, 256 ints)           gate indices int32 [B*K]
//   [1024 bytes, +12.6MB)   H [B*K, S, FF] bf16

// ---------------------------------------------------------------------------
// Gate: x_avg -> logits -> softmax -> top-2 (first-occurrence tie-break)
// ---------------------------------------------------------------------------
__global__ __launch_bounds__(256) void gate_kernel(
    const float* __restrict__ x, const float* __restrict__ Wg,
    const float* __restrict__ bg, float* __restrict__ out,
    int* __restrict__ gates)
{
    int b = blockIdx.x;
    int tid = threadIdx.x;

    float acc[EE];
#pragma unroll
    for (int e = 0; e < EE; ++e) acc[e] = 0.f;

    // each thread handles d = tid, tid+256, tid+512  (768 = 3*256)
    for (int d = tid; d < DD; d += 256) {
        float xs = 0.f;
        const float* xp = x + (size_t)b * SS * DD + d;
#pragma unroll
        for (int s = 0; s < SS; ++s) xs += xp[(size_t)s * DD];
#pragma unroll
        for (int e = 0; e < EE; ++e) acc[e] += xs * Wg[d * EE + e];
    }

    __shared__ float red[EE][256];
#pragma unroll
    for (int e = 0; e < EE; ++e) red[e][tid] = acc[e];
    __syncthreads();
    for (int off = 128; off > 0; off >>= 1) {
        if (tid < off) {
#pragma unroll
            for (int e = 0; e < EE; ++e) red[e][tid] += red[e][tid + off];
        }
        __syncthreads();
    }

    if (tid == 0) {
        float lg[EE], p[EE];
        float m = -1e30f;
#pragma unroll
        for (int e = 0; e < EE; ++e) {
            lg[e] = red[e][0] / (float)SS + bg[e];
            m = fmaxf(m, lg[e]);
        }
        float sum = 0.f;
#pragma unroll
        for (int e = 0; e < EE; ++e) { p[e] = expf(lg[e] - m); sum += p[e]; }
        float inv = 1.f / sum;
#pragma unroll
        for (int e = 0; e < EE; ++e) p[e] *= inv;

        // top-2, strict > keeps first occurrence (jax.lax.top_k tie rule)
        int i1 = 0;
        for (int e = 1; e < EE; ++e) if (p[e] > p[i1]) i1 = e;
        int i2 = (i1 == 0) ? 1 : 0;
        for (int e = 0; e < EE; ++e) if (e != i1 && p[e] > p[i2]) i2 = e;

        float* prob_out = out + (size_t)BB * SS * DD;
        float* gate_out = prob_out + BB * KK;
        prob_out[b * KK + 0] = p[i1];
        prob_out[b * KK + 1] = p[i2];
        gate_out[b * KK + 0] = (float)i1;
        gate_out[b * KK + 1] = (float)i2;
        gates[b * KK + 0] = i1;
        gates[b * KK + 1] = i2;
    }
}

// ---------------------------------------------------------------------------
// Init: out[b,s,d] = b2[e0,d] + b2[e1,d]  (bias pre-sum; down-proj atomicAdds)
// ---------------------------------------------------------------------------
__global__ __launch_bounds__(256) void init_kernel(
    const int* __restrict__ gates, const float* __restrict__ b2,
    float* __restrict__ out)
{
    int idx = blockIdx.x * 256 + threadIdx.x;
    if (idx >= BB * SS * DD) return;
    int b = idx / (SS * DD);
    int d = idx % DD;
    int e0 = gates[b * KK + 0];
    int e1 = gates[b * KK + 1];
    out[idx] = b2[e0 * DD + d] + b2[e1 * DD + d];
}

// ---------------------------------------------------------------------------
// Up-proj: H[pair,s,f] = gelu_exact( x[b] @ W1[e] + b1[e] ), bf16 to ws
// grid: (B*K, FF/128); block 256 = [32 s] x [128 f] tile, 16 acc/thread
// ---------------------------------------------------------------------------
__global__ __launch_bounds__(256) void up_kernel(
    const float* __restrict__ x, const float* __restrict__ W1,
    const float* __restrict__ b1, const int* __restrict__ gates,
    __hip_bfloat16* __restrict__ H)
{
    int pair = blockIdx.x;            // b*K + k
    int ft = blockIdx.y;              // f tile
    int b = pair >> 1;
    int e = gates[pair];
    int tid = threadIdx.x;
    int f = ft * 128 + (tid & 127);
    int shalf = tid >> 7;             // 0 or 1

    __shared__ float xs[SS][128];
    float acc[16];
#pragma unroll
    for (int i = 0; i < 16; ++i) acc[i] = 0.f;

    for (int d0 = 0; d0 < DD; d0 += 128) {
        __syncthreads();
        for (int i = tid; i < SS * 128; i += 256) {
            int s = i >> 7, dd = i & 127;
            xs[s][dd] = x[((size_t)b * SS + s) * DD + d0 + dd];
        }
        __syncthreads();
        const float* wp = W1 + ((size_t)e * DD + d0) * FF + f;
#pragma unroll 4
        for (int dd = 0; dd < 128; ++dd) {
            float w = wp[(size_t)dd * FF];
#pragma unroll
            for (int i = 0; i < 16; ++i)
                acc[i] += xs[shalf * 16 + i][dd] * w;
        }
    }

    float bias = b1[e * FF + f];
#pragma unroll
    for (int i = 0; i < 16; ++i) {
        int s = shalf * 16 + i;
        float h = acc[i] + bias;
        // exact gelu: 0.5*h*(1+erf(h/sqrt(2)))
        float g = 0.5f * h * (1.0f + erff(h * 0.70710678118654752f));
        H[((size_t)pair * SS + s) * FF + f] = __float2bfloat16(g);
    }
}

// ---------------------------------------------------------------------------
// Down-proj: out[b,s,d] += H[b,k] @ W2[e]   (atomicAdd fp32 partials)
// grid: (B, D/128, K*4); z = k*4 + f-quarter. block tile [32 s] x [128 d]
// ---------------------------------------------------------------------------
__global__ __launch_bounds__(256) void down_kernel(
    const __hip_bfloat16* __restrict__ H, const float* __restrict__ W2,
    const int* __restrict__ gates, float* __restrict__ out)
{
    int b = blockIdx.x;
    int dt = blockIdx.y;              // 0..5
    int kz = blockIdx.z;              // 0..7
    int k = kz >> 2, fs = kz & 3;
    int e = gates[b * KK + k];
    int tid = threadIdx.x;
    int d = dt * 128 + (tid & 127);
    int shalf = tid >> 7;

    __shared__ float hs[SS][128];
    float acc[16];
#pragma unroll
    for (int i = 0; i < 16; ++i) acc[i] = 0.f;

    const __hip_bfloat16* Hp = H + ((size_t)(b * KK + k)) * SS * FF;
    int fbeg = fs * (FF / 4);
    for (int f0 = fbeg; f0 < fbeg + FF / 4; f0 += 128) {
        __syncthreads();
        for (int i = tid; i < SS * 128; i += 256) {
            int s = i >> 7, ff = i & 127;
            hs[s][ff] = __bfloat162float(Hp[(size_t)s * FF + f0 + ff]);
        }
        __syncthreads();
        const float* wp = W2 + ((size_t)e * FF + f0) * DD + d;
#pragma unroll 4
        for (int ff = 0; ff < 128; ++ff) {
            float w = wp[(size_t)ff * DD];
#pragma unroll
            for (int i = 0; i < 16; ++i)
                acc[i] += hs[shalf * 16 + i][ff] * w;
        }
    }

#pragma unroll
    for (int i = 0; i < 16; ++i) {
        int s = shalf * 16 + i;
        atomicAdd(&out[((size_t)b * SS + s) * DD + d], acc[i]);
    }
}

// ---------------------------------------------------------------------------
extern "C" void kernel_launch(void* const* d_in, const int* in_sizes, int n_in,
                              void* d_out, int out_size, void* d_ws, size_t ws_size,
                              hipStream_t stream) {
    const float* x  = (const float*)d_in[0];
    // d_in[1] = attention_mask (unused: reference overwrites with ones)
    const float* Wg = (const float*)d_in[2];
    const float* bg = (const float*)d_in[3];
    const float* W1 = (const float*)d_in[4];
    const float* b1 = (const float*)d_in[5];
    const float* W2 = (const float*)d_in[6];
    const float* b2 = (const float*)d_in[7];
    float* out = (float*)d_out;

    int* gates = (int*)d_ws;
    __hip_bfloat16* H = (__hip_bfloat16*)((char*)d_ws + 1024);
    // ws needed: 1024 + B*K*S*FF*2 = ~12.6 MB

    gate_kernel<<<BB, 256, 0, stream>>>(x, Wg, bg, out, gates);
    init_kernel<<<(BB * SS * DD + 255) / 256, 256, 0, stream>>>(gates, b2, out);
    up_kernel<<<dim3(BB * KK, FF / 128), 256, 0, stream>>>(x, W1, b1, gates, H);
    down_kernel<<<dim3(BB, DD / 128, KK * 4), 256, 0, stream>>>(H, W2, gates, out);
}

// Round 2
// 140.281 us; speedup vs baseline: 3.2799x; 3.2799x over previous
//
#include <hip/hip_runtime.h>
#include <hip/hip_bf16.h>
#include <math.h>

#define BB 32
#define SS 32
#define DD 768
#define FFD 3072
#define EE 8
#define KK 2
#define NPAIR 64
#define MAXT 15

typedef __attribute__((ext_vector_type(8))) short short8;
typedef __attribute__((ext_vector_type(4))) float f32x4;
typedef __attribute__((ext_vector_type(4))) unsigned short us4;
typedef __attribute__((ext_vector_type(8))) unsigned short us8;

// ws int layout: [0..63] gates, [64..127] spair, [128..142] te_expert,
//                [144..158] te_slot0, [160..174] te_np
// H (bf16 [64*32][3072]) at ws byte offset 1024.

__device__ __forceinline__ unsigned short f2bf(float f) {
    __hip_bfloat16 h = __float2bfloat16(f);
    return __builtin_bit_cast(unsigned short, h);
}

// swizzled LDS byte offset: 128B rows, XOR bits 4-6 with row&7
__device__ __forceinline__ int lds_off(int row, int byte_in_row) {
    return row * 128 + (byte_in_row ^ ((row & 7) << 4));
}

// ---------------------------------------------------------------------------
__global__ __launch_bounds__(256) void gate_kernel(
    const float* __restrict__ x, const float* __restrict__ Wg,
    const float* __restrict__ bg, float* __restrict__ out,
    int* __restrict__ gates)
{
    int b = blockIdx.x;
    int tid = threadIdx.x;

    float acc[EE];
#pragma unroll
    for (int e = 0; e < EE; ++e) acc[e] = 0.f;

    for (int d = tid; d < DD; d += 256) {
        float xs = 0.f;
        const float* xp = x + (size_t)b * SS * DD + d;
#pragma unroll
        for (int s = 0; s < SS; ++s) xs += xp[(size_t)s * DD];
#pragma unroll
        for (int e = 0; e < EE; ++e) acc[e] += xs * Wg[d * EE + e];
    }

    __shared__ float red[EE][256];
#pragma unroll
    for (int e = 0; e < EE; ++e) red[e][tid] = acc[e];
    __syncthreads();
    for (int off = 128; off > 0; off >>= 1) {
        if (tid < off) {
#pragma unroll
            for (int e = 0; e < EE; ++e) red[e][tid] += red[e][tid + off];
        }
        __syncthreads();
    }

    if (tid == 0) {
        float lg[EE], p[EE];
        float m = -1e30f;
#pragma unroll
        for (int e = 0; e < EE; ++e) {
            lg[e] = red[e][0] / (float)SS + bg[e];
            m = fmaxf(m, lg[e]);
        }
        float sum = 0.f;
#pragma unroll
        for (int e = 0; e < EE; ++e) { p[e] = expf(lg[e] - m); sum += p[e]; }
        float inv = 1.f / sum;
#pragma unroll
        for (int e = 0; e < EE; ++e) p[e] *= inv;

        int i1 = 0;
        for (int e = 1; e < EE; ++e) if (p[e] > p[i1]) i1 = e;
        int i2 = (i1 == 0) ? 1 : 0;
        for (int e = 0; e < EE; ++e) if (e != i1 && p[e] > p[i2]) i2 = e;

        float* prob_out = out + (size_t)BB * SS * DD;
        float* gate_out = prob_out + BB * KK;
        prob_out[b * KK + 0] = p[i1];
        prob_out[b * KK + 1] = p[i2];
        gate_out[b * KK + 0] = (float)i1;
        gate_out[b * KK + 1] = (float)i2;
        gates[b * KK + 0] = i1;
        gates[b * KK + 1] = i2;
    }
}

// ---------------------------------------------------------------------------
// schedule: group pairs by expert, build tile table (BM=256 rows = 8 pairs)
__global__ void sched_kernel(int* __restrict__ wsi)
{
    if (threadIdx.x != 0 || blockIdx.x != 0) return;
    const int* gates = wsi;
    int* spair = wsi + 64;
    int* te_e = wsi + 128;
    int* te_s = wsi + 144;
    int* te_n = wsi + 160;

    int cnt[EE];
    for (int e = 0; e < EE; ++e) cnt[e] = 0;
    for (int p = 0; p < NPAIR; ++p) cnt[gates[p]]++;
    int start[EE + 1];
    start[0] = 0;
    for (int e = 0; e < EE; ++e) start[e + 1] = start[e] + cnt[e];
    int fill[EE];
    for (int e = 0; e < EE; ++e) fill[e] = start[e];
    for (int p = 0; p < NPAIR; ++p) spair[fill[gates[p]]++] = p;

    int t = 0;
    for (int e = 0; e < EE; ++e) {
        for (int o = 0; o < cnt[e]; o += 8) {
            te_e[t] = e;
            te_s[t] = start[e] + o;
            te_n[t] = (cnt[e] - o) < 8 ? (cnt[e] - o) : 8;
            ++t;
        }
    }
    for (; t < MAXT; ++t) te_n[t] = 0;
}

// ---------------------------------------------------------------------------
__global__ __launch_bounds__(256) void init_kernel(
    const int* __restrict__ gates, const float* __restrict__ b2,
    float* __restrict__ out)
{
    int idx = blockIdx.x * 256 + threadIdx.x;
    if (idx >= BB * SS * DD) return;
    int b = idx / (SS * DD);
    int d = idx % DD;
    int e0 = gates[b * KK + 0];
    int e1 = gates[b * KK + 1];
    out[idx] = b2[e0 * DD + d] + b2[e1 * DD + d];
}

// ---------------------------------------------------------------------------
// Up GEMM: H[grouped rows, f] = gelu(x @ W1[e] + b1[e]); BM=256 BN=64 BK=64
// grid (FFD/64=48, MAXT); 256 threads = 4 waves stacked in M.
__global__ __launch_bounds__(256) void up_gemm(
    const float* __restrict__ x, const float* __restrict__ W1,
    const float* __restrict__ b1, const int* __restrict__ wsi,
    __hip_bfloat16* __restrict__ H)
{
    int tile = blockIdx.y;
    int np = wsi[160 + tile];
    if (np == 0) return;
    int e = wsi[128 + tile];
    int slot0 = wsi[144 + tile];
    int nt = blockIdx.x;
    int tid = threadIdx.x;
    int wid = tid >> 6, lane = tid & 63;

    __shared__ char lds[40960];   // A [256][64]bf16 sw @0 (32KB), B [64][64]bf16 sw @32768
    char* Alds = lds;
    char* Blds = lds + 32768;

    f32x4 acc[4][4];
#pragma unroll
    for (int i = 0; i < 4; ++i)
#pragma unroll
        for (int j = 0; j < 4; ++j) acc[i][j] = (f32x4)0.f;

    for (int k0 = 0; k0 < DD; k0 += 64) {
        __syncthreads();
        // stage A: 256 rows x 16 float4-chunks
#pragma unroll
        for (int i = 0; i < 16; ++i) {
            int c = tid + i * 256;
            int row = c >> 4, kc = c & 15;
            int lp = row >> 5;
            int lpc = lp < np ? lp : np - 1;
            int pair = wsi[64 + slot0 + lpc];
            int b = pair >> 1;
            const float4* src = (const float4*)(x + ((size_t)(b * SS + (row & 31))) * DD + k0 + kc * 4);
            float4 v = *src;
            us4 u;
            u[0] = f2bf(v.x); u[1] = f2bf(v.y); u[2] = f2bf(v.z); u[3] = f2bf(v.w);
            if (lp >= np) { u[0] = 0; u[1] = 0; u[2] = 0; u[3] = 0; }
            *(us4*)(Alds + lds_off(row, kc * 8)) = u;
        }
        // stage B: [n][k] layout; lanes sweep n (coalesced), k strided
        {
            int n = tid & 63, kq = tid >> 6;
            const float* wp = W1 + ((size_t)e * DD + (k0 + kq * 16)) * FFD + (nt * 64 + n);
#pragma unroll
            for (int j4 = 0; j4 < 4; ++j4) {
                us4 u;
#pragma unroll
                for (int j = 0; j < 4; ++j)
                    u[j] = f2bf(wp[(size_t)(j4 * 4 + j) * FFD]);
                *(us4*)(Blds + lds_off(n, (kq * 16 + j4 * 4) * 2)) = u;
            }
        }
        __syncthreads();
#pragma unroll
        for (int kk = 0; kk < 2; ++kk) {
            int kb = (kk * 32 + (lane >> 4) * 8) * 2;
            short8 a[4], bf[4];
#pragma unroll
            for (int mf = 0; mf < 4; ++mf) {
                int row = wid * 64 + mf * 16 + (lane & 15);
                a[mf] = *(short8*)(Alds + lds_off(row, kb));
            }
#pragma unroll
            for (int nf = 0; nf < 4; ++nf) {
                int n = nf * 16 + (lane & 15);
                bf[nf] = *(short8*)(Blds + lds_off(n, kb));
            }
#pragma unroll
            for (int mf = 0; mf < 4; ++mf)
#pragma unroll
                for (int nf = 0; nf < 4; ++nf)
                    acc[mf][nf] = __builtin_amdgcn_mfma_f32_16x16x32_bf16(
                        a[mf], bf[nf], acc[mf][nf], 0, 0, 0);
        }
    }

    // epilogue: bias + exact gelu -> bf16 H (grouped rows)
    float bias[4];
#pragma unroll
    for (int nf = 0; nf < 4; ++nf)
        bias[nf] = b1[e * FFD + nt * 64 + nf * 16 + (lane & 15)];
#pragma unroll
    for (int mf = 0; mf < 4; ++mf) {
#pragma unroll
        for (int i = 0; i < 4; ++i) {
            int row = wid * 64 + mf * 16 + (lane >> 4) * 4 + i;
            int lp = row >> 5;
            if (lp >= np) continue;
            size_t srow = (size_t)(slot0 * 32 + row);
#pragma unroll
            for (int nf = 0; nf < 4; ++nf) {
                int f = nt * 64 + nf * 16 + (lane & 15);
                float h = acc[mf][nf][i] + bias[nf];
                float g = 0.5f * h * (1.0f + erff(h * 0.70710678118654752f));
                H[srow * FFD + f] = __float2bfloat16(g);
            }
        }
    }
}

// ---------------------------------------------------------------------------
// Down GEMM: out[b,s,:] += H @ W2[e]; BM=256 BN=64 BK=64, K split x2
// grid (DD/64=12, MAXT, 2)
__global__ __launch_bounds__(256) void down_gemm(
    const __hip_bfloat16* __restrict__ H, const float* __restrict__ W2,
    const int* __restrict__ wsi, float* __restrict__ out)
{
    int tile = blockIdx.y;
    int np = wsi[160 + tile];
    if (np == 0) return;
    int e = wsi[128 + tile];
    int slot0 = wsi[144 + tile];
    int nt = blockIdx.x;
    int zb = blockIdx.z * (FFD / 2);
    int tid = threadIdx.x;
    int wid = tid >> 6, lane = tid & 63;

    __shared__ char lds[40960];
    char* Alds = lds;
    char* Blds = lds + 32768;

    f32x4 acc[4][4];
#pragma unroll
    for (int i = 0; i < 4; ++i)
#pragma unroll
        for (int j = 0; j < 4; ++j) acc[i][j] = (f32x4)0.f;

    int maxrow = np * 32 - 1;
    for (int k0 = 0; k0 < FFD / 2; k0 += 64) {
        __syncthreads();
        // stage A from H (bf16, linear): 256 rows x 8 chunks of 8 bf16
#pragma unroll
        for (int i = 0; i < 8; ++i) {
            int c = tid + i * 256;
            int row = c >> 3, kc = c & 7;
            int rowc = row <= maxrow ? row : maxrow;
            us8 v = *(const us8*)(H + (size_t)(slot0 * 32 + rowc) * FFD + zb + k0 + kc * 8);
            *(us8*)(Alds + lds_off(row, kc * 16)) = v;
        }
        // stage B from W2 [f=k][d=n]
        {
            int n = tid & 63, kq = tid >> 6;
            const float* wp = W2 + ((size_t)e * FFD + (zb + k0 + kq * 16)) * DD + (nt * 64 + n);
#pragma unroll
            for (int j4 = 0; j4 < 4; ++j4) {
                us4 u;
#pragma unroll
                for (int j = 0; j < 4; ++j)
                    u[j] = f2bf(wp[(size_t)(j4 * 4 + j) * DD]);
                *(us4*)(Blds + lds_off(n, (kq * 16 + j4 * 4) * 2)) = u;
            }
        }
        __syncthreads();
#pragma unroll
        for (int kk = 0; kk < 2; ++kk) {
            int kb = (kk * 32 + (lane >> 4) * 8) * 2;
            short8 a[4], bf[4];
#pragma unroll
            for (int mf = 0; mf < 4; ++mf) {
                int row = wid * 64 + mf * 16 + (lane & 15);
                a[mf] = *(short8*)(Alds + lds_off(row, kb));
            }
#pragma unroll
            for (int nf = 0; nf < 4; ++nf) {
                int n = nf * 16 + (lane & 15);
                bf[nf] = *(short8*)(Blds + lds_off(n, kb));
            }
#pragma unroll
            for (int mf = 0; mf < 4; ++mf)
#pragma unroll
                for (int nf = 0; nf < 4; ++nf)
                    acc[mf][nf] = __builtin_amdgcn_mfma_f32_16x16x32_bf16(
                        a[mf], bf[nf], acc[mf][nf], 0, 0, 0);
        }
    }

    // epilogue: scatter-add into out (bias pre-added by init_kernel)
#pragma unroll
    for (int mf = 0; mf < 4; ++mf) {
#pragma unroll
        for (int i = 0; i < 4; ++i) {
            int row = wid * 64 + mf * 16 + (lane >> 4) * 4 + i;
            int lp = row >> 5;
            if (lp >= np) continue;
            int pair = wsi[64 + slot0 + lp];
            int b = pair >> 1;
            int s = row & 31;
            float* op = out + ((size_t)(b * SS + s)) * DD + nt * 64 + (lane & 15);
#pragma unroll
            for (int nf = 0; nf < 4; ++nf)
                atomicAdd(op + nf * 16, acc[mf][nf][i]);
        }
    }
}

// ---------------------------------------------------------------------------
extern "C" void kernel_launch(void* const* d_in, const int* in_sizes, int n_in,
                              void* d_out, int out_size, void* d_ws, size_t ws_size,
                              hipStream_t stream) {
    const float* x  = (const float*)d_in[0];
    const float* Wg = (const float*)d_in[2];
    const float* bg = (const float*)d_in[3];
    const float* W1 = (const float*)d_in[4];
    const float* b1 = (const float*)d_in[5];
    const float* W2 = (const float*)d_in[6];
    const float* b2 = (const float*)d_in[7];
    float* out = (float*)d_out;

    int* wsi = (int*)d_ws;
    __hip_bfloat16* H = (__hip_bfloat16*)((char*)d_ws + 1024);
    // ws needed: 1024 + 64*32*3072*2 = ~12.6 MB

    gate_kernel<<<BB, 256, 0, stream>>>(x, Wg, bg, out, wsi);
    sched_kernel<<<1, 64, 0, stream>>>(wsi);
    init_kernel<<<(BB * SS * DD + 255) / 256, 256, 0, stream>>>(wsi, b2, out);
    up_gemm<<<dim3(FFD / 64, MAXT), 256, 0, stream>>>(x, W1, b1, wsi, H);
    down_gemm<<<dim3(DD / 64, MAXT, 2), 256, 0, stream>>>(H, W2, wsi, out);
}

// Round 3
// 116.431 us; speedup vs baseline: 3.9518x; 1.2049x over previous
//
#include <hip/hip_runtime.h>
#include <hip/hip_bf16.h>
#include <math.h>

#define BB 32
#define SS 32
#define DD 768
#define FFD 3072
#define EE 8
#define KK 2
#define NPAIR 64
#define MAXT 22   // max expert-aligned tiles of 4 pairs: sum ceil(cnt/4) <= (64+24)/4

typedef __attribute__((ext_vector_type(8))) short short8;
typedef __attribute__((ext_vector_type(4))) float f32x4;
typedef __attribute__((ext_vector_type(8))) unsigned short us8;

// ws int layout: [0..63] gates, [64..127] spair (pairs grouped by expert),
//   [128..149] te_expert, [152..173] te_slot0, [176..197] te_np
// H (bf16 [64*32][3072]) at ws byte offset 1024.

__device__ __forceinline__ unsigned short f2bf(float f) {
    __hip_bfloat16 h = __float2bfloat16(f);
    return __builtin_bit_cast(unsigned short, h);
}

// swizzled LDS byte offset: 128B rows, XOR bits 4-6 with row&7 (st_16x32-style)
__device__ __forceinline__ int lds_off(int row, int byte_in_row) {
    return row * 128 + (byte_in_row ^ ((row & 7) << 4));
}

// ---------------------------------------------------------------------------
__global__ __launch_bounds__(256) void gate_kernel(
    const float* __restrict__ x, const float* __restrict__ Wg,
    const float* __restrict__ bg, float* __restrict__ out,
    int* __restrict__ gates)
{
    int b = blockIdx.x;
    int tid = threadIdx.x;

    float acc[EE];
#pragma unroll
    for (int e = 0; e < EE; ++e) acc[e] = 0.f;

    for (int d = tid; d < DD; d += 256) {
        float xs = 0.f;
        const float* xp = x + (size_t)b * SS * DD + d;
#pragma unroll
        for (int s = 0; s < SS; ++s) xs += xp[(size_t)s * DD];
#pragma unroll
        for (int e = 0; e < EE; ++e) acc[e] += xs * Wg[d * EE + e];
    }

    __shared__ float red[EE][256];
#pragma unroll
    for (int e = 0; e < EE; ++e) red[e][tid] = acc[e];
    __syncthreads();
    for (int off = 128; off > 0; off >>= 1) {
        if (tid < off) {
#pragma unroll
            for (int e = 0; e < EE; ++e) red[e][tid] += red[e][tid + off];
        }
        __syncthreads();
    }

    if (tid == 0) {
        float lg[EE], p[EE];
        float m = -1e30f;
#pragma unroll
        for (int e = 0; e < EE; ++e) {
            lg[e] = red[e][0] / (float)SS + bg[e];
            m = fmaxf(m, lg[e]);
        }
        float sum = 0.f;
#pragma unroll
        for (int e = 0; e < EE; ++e) { p[e] = expf(lg[e] - m); sum += p[e]; }
        float inv = 1.f / sum;
#pragma unroll
        for (int e = 0; e < EE; ++e) p[e] *= inv;

        int i1 = 0;
        for (int e = 1; e < EE; ++e) if (p[e] > p[i1]) i1 = e;
        int i2 = (i1 == 0) ? 1 : 0;
        for (int e = 0; e < EE; ++e) if (e != i1 && p[e] > p[i2]) i2 = e;

        float* prob_out = out + (size_t)BB * SS * DD;
        float* gate_out = prob_out + BB * KK;
        prob_out[b * KK + 0] = p[i1];
        prob_out[b * KK + 1] = p[i2];
        gate_out[b * KK + 0] = (float)i1;
        gate_out[b * KK + 1] = (float)i2;
        gates[b * KK + 0] = i1;
        gates[b * KK + 1] = i2;
    }
}

// ---------------------------------------------------------------------------
// schedule: group pairs by expert, tiles of 4 pairs (BM=128 rows)
__global__ void sched_kernel(int* __restrict__ wsi)
{
    if (threadIdx.x != 0 || blockIdx.x != 0) return;
    const int* gates = wsi;
    int* spair = wsi + 64;
    int* te_e = wsi + 128;
    int* te_s = wsi + 152;
    int* te_n = wsi + 176;

    int cnt[EE];
    for (int e = 0; e < EE; ++e) cnt[e] = 0;
    for (int p = 0; p < NPAIR; ++p) cnt[gates[p]]++;
    int start[EE + 1];
    start[0] = 0;
    for (int e = 0; e < EE; ++e) start[e + 1] = start[e] + cnt[e];
    int fill[EE];
    for (int e = 0; e < EE; ++e) fill[e] = start[e];
    for (int p = 0; p < NPAIR; ++p) spair[fill[gates[p]]++] = p;

    int t = 0;
    for (int e = 0; e < EE; ++e) {
        for (int o = 0; o < cnt[e]; o += 4) {
            te_e[t] = e;
            te_s[t] = start[e] + o;
            te_n[t] = (cnt[e] - o) < 4 ? (cnt[e] - o) : 4;
            ++t;
        }
    }
    for (; t < MAXT; ++t) te_n[t] = 0;
}

// ---------------------------------------------------------------------------
__global__ __launch_bounds__(256) void init_kernel(
    const int* __restrict__ gates, const float* __restrict__ b2,
    float* __restrict__ out)
{
    int idx = blockIdx.x * 256 + threadIdx.x;
    if (idx >= BB * SS * DD) return;
    int b = idx / (SS * DD);
    int d = idx % DD;
    int e0 = gates[b * KK + 0];
    int e1 = gates[b * KK + 1];
    out[idx] = b2[e0 * DD + d] + b2[e1 * DD + d];
}

// ---------------------------------------------------------------------------
// Up GEMM: H = gelu(x @ W1[e] + b1[e]); BM=128 BN=128 BK=64, 4 waves 2x2,
// reg-staged + LDS double-buffered (T14), one barrier per K-step.
// grid (FFD/128=24, MAXT)
__global__ __launch_bounds__(256, 2) void up_gemm(
    const float* __restrict__ x, const float* __restrict__ W1,
    const float* __restrict__ b1, const int* __restrict__ wsi,
    unsigned short* __restrict__ H)
{
    int tile = blockIdx.y;
    int np = wsi[176 + tile];
    if (np == 0) return;
    int e = wsi[128 + tile];
    int slot0 = wsi[152 + tile];
    int nt = blockIdx.x;
    int tid = threadIdx.x;
    int wid = tid >> 6, lane = tid & 63;
    int wm = wid >> 1, wn = wid & 1;

    __shared__ char lds[65536];   // per buf: A 16KB + B 16KB; two bufs

    // A staging setup (x fp32 gathered rows -> bf16)
    const float* asrc[4];
    bool aval[4];
    int aoff[4];
#pragma unroll
    for (int i = 0; i < 4; ++i) {
        int c = tid + i * 256;            // 0..1023
        int row = c >> 3, ch = c & 7;     // 128 rows x 8 chunks of 8 elems
        int lp = row >> 5;
        int lpc = lp < np ? lp : np - 1;
        int pair = wsi[64 + slot0 + lpc];
        int b = pair >> 1;
        asrc[i] = x + ((size_t)(b * SS + (row & 31))) * DD + ch * 8;
        aval[i] = lp < np;
        aoff[i] = lds_off(row, ch * 16);
    }
    // B staging setup: [n][k] LDS; lane sweeps n (coalesced), k strided
    int n = tid & 127, kq = tid >> 7;
    const float* bsrc = W1 + ((size_t)e * DD + kq * 32) * FFD + nt * 128 + n;
    int boff[4];
#pragma unroll
    for (int jj = 0; jj < 4; ++jj) boff[jj] = lds_off(n, kq * 64 + jj * 16);

    f32x4 acc[4][4];
#pragma unroll
    for (int i = 0; i < 4; ++i)
#pragma unroll
        for (int j = 0; j < 4; ++j) acc[i][j] = (f32x4)0.f;

    float brg[32];
    float4 a4[4][2];

    auto issue = [&](int k0) {
        const float* wp = bsrc + (size_t)k0 * FFD;   // cold HBM stream first
#pragma unroll
        for (int j = 0; j < 32; ++j) brg[j] = wp[(size_t)j * FFD];
#pragma unroll
        for (int i = 0; i < 4; ++i) {
            if (aval[i]) {
                a4[i][0] = *(const float4*)(asrc[i] + k0);
                a4[i][1] = *(const float4*)(asrc[i] + k0 + 4);
            }
        }
    };
    auto store = [&](int p) {
        char* Al = lds + p * 32768;
        char* Bl = Al + 16384;
#pragma unroll
        for (int i = 0; i < 4; ++i) {
            us8 u;
            if (aval[i]) {
                u[0] = f2bf(a4[i][0].x); u[1] = f2bf(a4[i][0].y);
                u[2] = f2bf(a4[i][0].z); u[3] = f2bf(a4[i][0].w);
                u[4] = f2bf(a4[i][1].x); u[5] = f2bf(a4[i][1].y);
                u[6] = f2bf(a4[i][1].z); u[7] = f2bf(a4[i][1].w);
            } else {
#pragma unroll
                for (int m = 0; m < 8; ++m) u[m] = 0;
            }
            *(us8*)(Al + aoff[i]) = u;
        }
#pragma unroll
        for (int jj = 0; jj < 4; ++jj) {
            us8 u;
#pragma unroll
            for (int m = 0; m < 8; ++m) u[m] = f2bf(brg[jj * 8 + m]);
            *(us8*)(Bl + boff[jj]) = u;
        }
    };
    auto compute = [&](int p) {
        char* Al = lds + p * 32768;
        char* Bl = Al + 16384;
#pragma unroll
        for (int kk = 0; kk < 2; ++kk) {
            int kb = kk * 64 + (lane >> 4) * 16;
            short8 af[4], bf[4];
#pragma unroll
            for (int mf = 0; mf < 4; ++mf)
                af[mf] = *(short8*)(Al + lds_off(wm * 64 + mf * 16 + (lane & 15), kb));
#pragma unroll
            for (int nf = 0; nf < 4; ++nf)
                bf[nf] = *(short8*)(Bl + lds_off(wn * 64 + nf * 16 + (lane & 15), kb));
#pragma unroll
            for (int mf = 0; mf < 4; ++mf)
#pragma unroll
                for (int nf = 0; nf < 4; ++nf)
                    acc[mf][nf] = __builtin_amdgcn_mfma_f32_16x16x32_bf16(
                        af[mf], bf[nf], acc[mf][nf], 0, 0, 0);
        }
    };

    issue(0);
    store(0);
    issue(64);
    __syncthreads();
#pragma unroll 2
    for (int s = 0; s < 12; ++s) {
        int p = s & 1;
        compute(p);
        if (s < 11) {
            store(p ^ 1);
            if (s < 10) issue((s + 2) * 64);
        }
        __syncthreads();
    }

    // epilogue: bias + exact gelu -> bf16 H (grouped slot rows)
    float bias[4];
#pragma unroll
    for (int nf = 0; nf < 4; ++nf)
        bias[nf] = b1[e * FFD + nt * 128 + wn * 64 + nf * 16 + (lane & 15)];
#pragma unroll
    for (int mf = 0; mf < 4; ++mf) {
#pragma unroll
        for (int i = 0; i < 4; ++i) {
            int row = wm * 64 + mf * 16 + (lane >> 4) * 4 + i;
            if ((row >> 5) >= np) continue;
            size_t srow = (size_t)(slot0 * 32 + row);
#pragma unroll
            for (int nf = 0; nf < 4; ++nf) {
                int f = nt * 128 + wn * 64 + nf * 16 + (lane & 15);
                float h = acc[mf][nf][i] + bias[nf];
                float g = 0.5f * h * (1.0f + erff(h * 0.70710678118654752f));
                H[srow * FFD + f] = f2bf(g);
            }
        }
    }
}

// ---------------------------------------------------------------------------
// Down GEMM: out += H @ W2[e]; BM=128 BN=128 BK=64, K split x4, same pipeline.
// grid (DD/128=6, MAXT, 4)
__global__ __launch_bounds__(256, 2) void down_gemm(
    const unsigned short* __restrict__ H, const float* __restrict__ W2,
    const int* __restrict__ wsi, float* __restrict__ out)
{
    int tile = blockIdx.y;
    int np = wsi[176 + tile];
    if (np == 0) return;
    int e = wsi[128 + tile];
    int slot0 = wsi[152 + tile];
    int nt = blockIdx.x;
    int zb = blockIdx.z * (FFD / 4);
    int tid = threadIdx.x;
    int wid = tid >> 6, lane = tid & 63;
    int wm = wid >> 1, wn = wid & 1;

    __shared__ char lds[65536];

    // A staging setup (H bf16, contiguous grouped rows; clamp tail rows)
    const unsigned short* asrc[4];
    int aoff[4];
#pragma unroll
    for (int i = 0; i < 4; ++i) {
        int c = tid + i * 256;
        int row = c >> 3, ch = c & 7;
        int rc = row < np * 32 ? row : np * 32 - 1;
        asrc[i] = H + (size_t)(slot0 * 32 + rc) * FFD + zb + ch * 8;
        aoff[i] = lds_off(row, ch * 16);
    }
    int n = tid & 127, kq = tid >> 7;
    const float* bsrc = W2 + ((size_t)e * FFD + zb + kq * 32) * DD + nt * 128 + n;
    int boff[4];
#pragma unroll
    for (int jj = 0; jj < 4; ++jj) boff[jj] = lds_off(n, kq * 64 + jj * 16);

    f32x4 acc[4][4];
#pragma unroll
    for (int i = 0; i < 4; ++i)
#pragma unroll
        for (int j = 0; j < 4; ++j) acc[i][j] = (f32x4)0.f;

    float brg[32];
    us8 arg[4];

    auto issue = [&](int k0) {
        const float* wp = bsrc + (size_t)k0 * DD;
#pragma unroll
        for (int j = 0; j < 32; ++j) brg[j] = wp[(size_t)j * DD];
#pragma unroll
        for (int i = 0; i < 4; ++i) arg[i] = *(const us8*)(asrc[i] + k0);
    };
    auto store = [&](int p) {
        char* Al = lds + p * 32768;
        char* Bl = Al + 16384;
#pragma unroll
        for (int i = 0; i < 4; ++i) *(us8*)(Al + aoff[i]) = arg[i];
#pragma unroll
        for (int jj = 0; jj < 4; ++jj) {
            us8 u;
#pragma unroll
            for (int m = 0; m < 8; ++m) u[m] = f2bf(brg[jj * 8 + m]);
            *(us8*)(Bl + boff[jj]) = u;
        }
    };
    auto compute = [&](int p) {
        char* Al = lds + p * 32768;
        char* Bl = Al + 16384;
#pragma unroll
        for (int kk = 0; kk < 2; ++kk) {
            int kb = kk * 64 + (lane >> 4) * 16;
            short8 af[4], bf[4];
#pragma unroll
            for (int mf = 0; mf < 4; ++mf)
                af[mf] = *(short8*)(Al + lds_off(wm * 64 + mf * 16 + (lane & 15), kb));
#pragma unroll
            for (int nf = 0; nf < 4; ++nf)
                bf[nf] = *(short8*)(Bl + lds_off(wn * 64 + nf * 16 + (lane & 15), kb));
#pragma unroll
            for (int mf = 0; mf < 4; ++mf)
#pragma unroll
                for (int nf = 0; nf < 4; ++nf)
                    acc[mf][nf] = __builtin_amdgcn_mfma_f32_16x16x32_bf16(
                        af[mf], bf[nf], acc[mf][nf], 0, 0, 0);
        }
    };

    issue(0);
    store(0);
    issue(64);
    __syncthreads();
#pragma unroll 2
    for (int s = 0; s < 12; ++s) {
        int p = s & 1;
        compute(p);
        if (s < 11) {
            store(p ^ 1);
            if (s < 10) issue((s + 2) * 64);
        }
        __syncthreads();
    }

    // epilogue: scatter atomic-add (bias pre-added by init_kernel)
#pragma unroll
    for (int mf = 0; mf < 4; ++mf) {
#pragma unroll
        for (int i = 0; i < 4; ++i) {
            int row = wm * 64 + mf * 16 + (lane >> 4) * 4 + i;
            int lp = row >> 5;
            if (lp >= np) continue;
            int pair = wsi[64 + slot0 + lp];
            int b = pair >> 1;
            int sI = row & 31;
            float* op = out + ((size_t)(b * SS + sI)) * DD + nt * 128 + wn * 64 + (lane & 15);
#pragma unroll
            for (int nf = 0; nf < 4; ++nf)
                atomicAdd(op + nf * 16, acc[mf][nf][i]);
        }
    }
}

// ---------------------------------------------------------------------------
extern "C" void kernel_launch(void* const* d_in, const int* in_sizes, int n_in,
                              void* d_out, int out_size, void* d_ws, size_t ws_size,
                              hipStream_t stream) {
    const float* x  = (const float*)d_in[0];
    const float* Wg = (const float*)d_in[2];
    const float* bg = (const float*)d_in[3];
    const float* W1 = (const float*)d_in[4];
    const float* b1 = (const float*)d_in[5];
    const float* W2 = (const float*)d_in[6];
    const float* b2 = (const float*)d_in[7];
    float* out = (float*)d_out;

    int* wsi = (int*)d_ws;
    unsigned short* H = (unsigned short*)((char*)d_ws + 1024);
    // ws needed: 1024 + 64*32*3072*2 = ~12.6 MB

    gate_kernel<<<BB, 256, 0, stream>>>(x, Wg, bg, out, wsi);
    sched_kernel<<<1, 64, 0, stream>>>(wsi);
    init_kernel<<<(BB * SS * DD + 255) / 256, 256, 0, stream>>>(wsi, b2, out);
    up_gemm<<<dim3(FFD / 128, MAXT), 256, 0, stream>>>(x, W1, b1, wsi, H);
    down_gemm<<<dim3(DD / 128, MAXT, 4), 256, 0, stream>>>(H, W2, wsi, out);
}